// Round 3
// baseline (1971.438 us; speedup 1.0000x reference)
//
#include <hip/hip_runtime.h>
#include <hip/hip_bf16.h>

#define B_ 8
#define K_ 8
#define H_ 256
#define W_ 256
#define HW (H_*W_)

// ---------------------------------------------------------------------------
// helpers
// ---------------------------------------------------------------------------
__device__ __forceinline__ unsigned short f2bf(float f) {
    __hip_bfloat16 h = __float2bfloat16(f);  // RNE
    return *reinterpret_cast<unsigned short*>(&h);
}
// unpack 8 bf16 (packed pairs: elem 2k low 16 bits, 2k+1 high) to f32
__device__ __forceinline__ void ub8(uint4 u, float* o) {
    o[0] = __uint_as_float(u.x << 16); o[1] = __uint_as_float(u.x & 0xffff0000u);
    o[2] = __uint_as_float(u.y << 16); o[3] = __uint_as_float(u.y & 0xffff0000u);
    o[4] = __uint_as_float(u.z << 16); o[5] = __uint_as_float(u.z & 0xffff0000u);
    o[6] = __uint_as_float(u.w << 16); o[7] = __uint_as_float(u.w & 0xffff0000u);
}

// ---------------------------------------------------------------------------
// prep: transpose img/temp to channel-interleaved bf16/f32, compute grads,
// accumulate 8x8 Gram (f32 pixel -> f32 block tree -> f64 atomics),
// last-block-per-batch: invert 8x8 (f64 Gauss-Jordan) + init p/dp.
// grid = B_*H_ blocks (one per (b,y) row), 256 threads (one per x).
// ---------------------------------------------------------------------------
__global__ __launch_bounds__(256) void prep_kernel(
    const float* __restrict__ img, const float* __restrict__ temp,
    const float* __restrict__ init_param,
    uint4* __restrict__ imgT, uint4* __restrict__ TG,
    double* __restrict__ Hacc, double* __restrict__ invH,
    double* __restrict__ p, double* __restrict__ dp,
    int* __restrict__ tickets) {
    __shared__ float smem[9472];   // rows: 8192 floats; reused for 256x37 reduce
    __shared__ double shd[128];
    __shared__ int sh_last;
    const int b   = blockIdx.x >> 8;
    const int y   = blockIdx.x & 255;
    const int tid = threadIdx.x;
    const int ym = (y > 0) ? y - 1 : 0;
    const int yp = (y < 255) ? y + 1 : 255;

    // stage 32 rows (8ch x {ym,y,yp,img-y}) as float4s: 2048 slots, 8/thread
    #pragma unroll
    for (int j = 0; j < 8; ++j) {
        const int slot = tid + 256 * j;
        const int rowid = slot >> 6, col4 = slot & 63;
        const int c = rowid >> 2, sel = rowid & 3;
        const int sy = (sel == 0) ? ym : ((sel == 2) ? yp : y);
        const float* src = ((sel == 3) ? img : temp)
                         + ((size_t)(b * K_ + c) * HW + sy * W_ + col4 * 4);
        const float4 v = *(const float4*)src;
        *(float4*)&smem[(c * 4 + sel) * 256 + col4 * 4] = v;
    }
    __syncthreads();

    const int x = tid;
    const int px = (y << 8) | x;
    const float X = (float)x - 127.5f, Y = (float)y - 127.5f;
    const int xm = (x > 0) ? x - 1 : 0;
    const int xp = (x < 255) ? x + 1 : 255;
    float Sxx = 0.f, Sxy = 0.f, Syy = 0.f;
    unsigned int imgp[4] = {0, 0, 0, 0};
    unsigned int tgp[16];
    #pragma unroll
    for (int i = 8; i < 16; ++i) tgp[i] = 0u;
    #pragma unroll
    for (int c = 0; c < 8; ++c) {
        const float* R = &smem[c * 1024];
        const float gx = 0.5f * (R[256 + xp] - R[256 + xm]);
        const float gy = 0.5f * (R[512 + x] - R[x]);
        const float tc = R[256 + x];
        const float iv = R[768 + x];
        Sxx += gx * gx; Sxy += gx * gy; Syy += gy * gy;
        const int sh = (c & 1) * 16;
        imgp[c >> 1]      |= ((unsigned int)f2bf(iv)) << sh;
        tgp[c]             = __float_as_uint(tc);
        tgp[8 + (c >> 1)] |= ((unsigned int)f2bf(gx)) << sh;
        tgp[12 + (c >> 1)]|= ((unsigned int)f2bf(gy)) << sh;
    }
    const size_t gpx = (size_t)b * HW + px;
    imgT[gpx] = make_uint4(imgp[0], imgp[1], imgp[2], imgp[3]);
    uint4* tg = TG + gpx * 4;
    tg[0] = make_uint4(tgp[0],  tgp[1],  tgp[2],  tgp[3]);
    tg[1] = make_uint4(tgp[4],  tgp[5],  tgp[6],  tgp[7]);
    tg[2] = make_uint4(tgp[8],  tgp[9],  tgp[10], tgp[11]);
    tg[3] = make_uint4(tgp[12], tgp[13], tgp[14], tgp[15]);
    __syncthreads();   // rows consumed; reuse smem for Gram reduce

    {   // expand (Sxx,Sxy,Syy) to 36 upper-tri Gram entries via J = M(px)*(gx,gy)
        const float av[8] = {X, Y, 1.f, 0.f, 0.f, 0.f, -X * X, -X * Y};
        const float bv[8] = {0.f, 0.f, 0.f, X, Y, 1.f, -X * Y, -Y * Y};
        int idx = 0;
        #pragma unroll
        for (int pi = 0; pi < 8; ++pi)
            #pragma unroll
            for (int qi = pi; qi < 8; ++qi) {
                smem[tid * 37 + idx] = av[pi] * av[qi] * Sxx
                    + (av[pi] * bv[qi] + av[qi] * bv[pi]) * Sxy
                    + bv[pi] * bv[qi] * Syy;
                ++idx;
            }
    }
    __syncthreads();
    #pragma unroll
    for (int st = 128; st >= 1; st >>= 1) {
        if (tid < st) {
            #pragma unroll
            for (int e = 0; e < 36; ++e)
                smem[tid * 37 + e] += smem[(tid + st) * 37 + e];
        }
        __syncthreads();
    }
    if (tid < 36) atomicAdd(&Hacc[b * 36 + tid], (double)smem[tid]);
    __threadfence();
    if (tid == 0) sh_last = (atomicAdd(&tickets[8 + b], 1) == 255) ? 1 : 0;
    __syncthreads();
    if (!sh_last) return;

    // last block of batch b: read Gram via atomics, invert, init p/dp
    const int i = tid >> 3, j = tid & 7;
    if (tid < 64) {
        const int pp = min(i, j), qq = max(i, j);
        const int tri = 8 * pp - (pp * (pp - 1)) / 2 + (qq - pp);
        shd[tid]      = atomicAdd(&Hacc[b * 36 + tri], 0.0);
        shd[64 + tid] = (i == j) ? 1.0 : 0.0;
    }
    __syncthreads();
    for (int k = 0; k < 8; ++k) {
        const double piv = (tid < 64) ? shd[k * 8 + k] : 1.0;
        __syncthreads();
        if (tid < 64 && i == k) { shd[tid] /= piv; shd[64 + tid] /= piv; }
        __syncthreads();
        double f = 0, ak = 0, bk = 0;
        if (tid < 64) { f = shd[i * 8 + k]; ak = shd[k * 8 + j]; bk = shd[64 + k * 8 + j]; }
        __syncthreads();
        if (tid < 64 && i != k) { shd[tid] -= f * ak; shd[64 + tid] -= f * bk; }
        __syncthreads();
    }
    if (tid < 64) invH[b * 64 + tid] = shd[64 + tid];
    if (tid < 8) { p[b * 8 + tid] = (double)init_param[b * 8 + tid]; dp[b * 8 + tid] = 1.0; }
}

// ---------------------------------------------------------------------------
// per-iteration: warp + bilinear (8ch via one dwordx4 per corner) + residual
// + s-accumulate (f32 block tree -> f64 atomic); last block per batch does
// the dp/p update in-kernel (ticket + device-scope atomics).
// grid = B_*H_ blocks, 256 threads, 1 px/thread.
// ---------------------------------------------------------------------------
__global__ __launch_bounds__(256) void iter_kernel(
    const uint4* __restrict__ imgT, const uint4* __restrict__ TG,
    const double* __restrict__ invH,
    double* __restrict__ p, double* __restrict__ dp, double* __restrict__ s,
    int* __restrict__ tickets, const int* __restrict__ max_itr, int iter) {
    if (iter >= *max_itr) return;
    __shared__ float red[2304];
    __shared__ double sh_sd[8];
    __shared__ int sh_last;
    const int b   = blockIdx.x >> 8;
    const int tid = threadIdx.x;
    const int y = blockIdx.x & 255, x = tid;
    const int px = (y << 8) | x;

    const double* pb = p + b * 8;
    const float h00 = 1.f + (float)pb[0], h01 = (float)pb[1], h02 = (float)pb[2];
    const float h10 = (float)pb[3], h11 = 1.f + (float)pb[4], h12 = (float)pb[5];
    const float h20 = (float)pb[6], h21 = (float)pb[7];

    const float X = (float)x - 127.5f, Y = (float)y - 127.5f;
    const float zw = h20 * X + h21 * Y + 1.f;
    const float Xw = (h00 * X + h01 * Y + h02) / zw + 127.5f;
    const float Yw = (h10 * X + h11 * Y + h12) / zw + 127.5f;
    const float NLO = -1.f + 2.f / 256.f, NHI = 1.f - 2.f / 256.f;
    const float xn = Xw / 127.5f - 1.f, yn = Yw / 127.5f - 1.f;
    const float m = (xn > NLO && xn < NHI && yn > NLO && yn < NHI) ? 1.f : 0.f;

    const float x0f = floorf(Xw), y0f = floorf(Yw);
    const float fx = Xw - x0f, fy = Yw - y0f;
    const float x1f = x0f + 1.f, y1f = y0f + 1.f;
    const bool vx0 = (x0f >= 0.f) && (x0f <= 255.f);
    const bool vx1 = (x1f >= 0.f) && (x1f <= 255.f);
    const bool vy0 = (y0f >= 0.f) && (y0f <= 255.f);
    const bool vy1 = (y1f >= 0.f) && (y1f <= 255.f);
    const int xi0 = (int)fminf(fmaxf(x0f, 0.f), 255.f);
    const int xi1 = (int)fminf(fmaxf(x1f, 0.f), 255.f);
    const int yi0 = (int)fminf(fmaxf(y0f, 0.f), 255.f);
    const int yi1 = (int)fminf(fmaxf(y1f, 0.f), 255.f);
    const int i00 = yi0 * W_ + xi0, i01 = yi0 * W_ + xi1;
    const int i10 = yi1 * W_ + xi0, i11 = yi1 * W_ + xi1;
    const float w00 = ((vx0 && vy0) ? 1.f : 0.f) * (1.f - fx) * (1.f - fy);
    const float w01 = ((vx1 && vy0) ? 1.f : 0.f) * fx * (1.f - fy);
    const float w10 = ((vx0 && vy1) ? 1.f : 0.f) * (1.f - fx) * fy;
    const float w11 = ((vx1 && vy1) ? 1.f : 0.f) * fx * fy;

    const int base = b * HW;
    const uint4 u00 = imgT[base + i00], u01 = imgT[base + i01];
    const uint4 u10 = imgT[base + i10], u11 = imgT[base + i11];
    const uint4* tg = TG + (size_t)(base + px) * 4;
    const uint4 t0 = tg[0], t1 = tg[1], g0 = tg[2], g1 = tg[3];

    float A00[8], A01[8], A10[8], A11[8], GX[8], GY[8], TV[8];
    ub8(u00, A00); ub8(u01, A01); ub8(u10, A10); ub8(u11, A11);
    ub8(g0, GX);   ub8(g1, GY);
    TV[0] = __uint_as_float(t0.x); TV[1] = __uint_as_float(t0.y);
    TV[2] = __uint_as_float(t0.z); TV[3] = __uint_as_float(t0.w);
    TV[4] = __uint_as_float(t1.x); TV[5] = __uint_as_float(t1.y);
    TV[6] = __uint_as_float(t1.z); TV[7] = __uint_as_float(t1.w);

    float vx = 0.f, vy = 0.f;
    #pragma unroll
    for (int c = 0; c < 8; ++c) {
        const float Q = w00 * A00[c] + w01 * A01[c] + w10 * A10[c] + w11 * A11[c];
        const float r = Q - TV[c] * m;
        vx += GX[c] * r;
        vy += GY[c] * r;
    }
    float a[8];
    a[0] = X * vx; a[1] = Y * vx; a[2] = vx;
    a[3] = X * vy; a[4] = Y * vy; a[5] = vy;
    const float cc = a[0] + a[4];
    a[6] = -X * cc; a[7] = -Y * cc;

    #pragma unroll
    for (int e = 0; e < 8; ++e) red[tid * 8 + e] = a[e];
    __syncthreads();
    float part = 0.f;
    #pragma unroll
    for (int j2 = 0; j2 < 8; ++j2) part += red[tid + 256 * j2];  // entry tid&7
    red[2048 + tid] = part;
    __syncthreads();
    if (tid < 8) {
        double v = 0.0;
        #pragma unroll
        for (int u = 0; u < 32; ++u) v += (double)red[2048 + u * 8 + tid];
        atomicAdd(&s[b * 8 + tid], v);
    }
    __threadfence();
    if (tid == 0) sh_last = (atomicAdd(&tickets[b], 1) == 255) ? 1 : 0;
    __syncthreads();
    if (!sh_last) return;

    // last block of batch b: dp = invH @ s, freeze, p -= dp, reset s/ticket
    if (tid < 8) sh_sd[tid] = atomicAdd(&s[b * 8 + tid], 0.0);
    __syncthreads();
    if (tid < 8) {
        double nrm2 = 0.0;
        #pragma unroll
        for (int k2 = 0; k2 < 8; ++k2) { const double d = dp[b * 8 + k2]; nrm2 += d * d; }
        double dpn = 0.0;
        if (tid < 6) {
            #pragma unroll
            for (int k2 = 0; k2 < 8; ++k2) dpn += invH[b * 64 + tid * 8 + k2] * sh_sd[k2];
        }
        const double dp2 = (sqrt(nrm2) > 1e-3) ? dpn : 0.0;
        p[b * 8 + tid] -= dp2;
        dp[b * 8 + tid] = dp2;
        s[b * 8 + tid] = 0.0;
        if (tid == 0) tickets[b] = 0;
    }
}

// ---------------------------------------------------------------------------
// output: p (64 f32), then H = param_to_H(p) (72 f32)
// ---------------------------------------------------------------------------
__global__ void output_kernel(const double* __restrict__ p, float* __restrict__ out) {
    const int t = threadIdx.x;  // 128
    if (t < 64) out[t] = (float)p[t];
    if (t < 72) {
        const int b = t / 9, j = t % 9;
        float v = (j < 8) ? (float)p[b * 8 + j] : 0.f;
        if (j == 0 || j == 4 || j == 8) v += 1.f;
        out[64 + t] = v;
    }
}

extern "C" void kernel_launch(void* const* d_in, const int* in_sizes, int n_in,
                              void* d_out, int out_size, void* d_ws, size_t ws_size,
                              hipStream_t stream) {
    const float* img        = (const float*)d_in[0];
    const float* temp       = (const float*)d_in[1];
    const float* init_param = (const float*)d_in[2];
    const int*   max_itr    = (const int*)d_in[3];
    float* out = (float*)d_out;

    char* w = (char*)d_ws;
    double* Hacc   = (double*)w;                    // 288 d @ 0
    double* s      = Hacc + 288;                    // 64 d  @ 2304
    int*   tickets = (int*)(s + 64);                // 16 i  @ 2816
    double* invH   = (double*)(w + 3072);           // 512 d
    double* p      = invH + 512;                    // 64 d  @ 7168
    double* dp     = p + 64;                        // 64 d  @ 7680
    uint4* imgT    = (uint4*)(w + 16384);           // 8.39 MB (bf16 x8 per px)
    uint4* TG      = (uint4*)(w + 16384 + 8388608); // 33.55 MB (Tv f32x8 + g bf16x16)

    // zero Hacc + s + tickets (poisoned 0xAA by harness before every launch)
    hipMemsetAsync(d_ws, 0, 4096, stream);

    prep_kernel<<<B_ * H_, 256, 0, stream>>>(img, temp, init_param, imgT, TG,
                                             Hacc, invH, p, dp, tickets);
    for (int it = 0; it < 10; ++it) {
        iter_kernel<<<B_ * H_, 256, 0, stream>>>(imgT, TG, invH, p, dp, s,
                                                 tickets, max_itr, it);
    }
    output_kernel<<<1, 128, 0, stream>>>(p, out);
}

// Round 4
// 285.524 us; speedup vs baseline: 6.9046x; 6.9046x over previous
//
#include <hip/hip_runtime.h>
#include <hip/hip_bf16.h>

#define B_ 8
#define K_ 8
#define H_ 256
#define W_ 256
#define HW (H_*W_)

// ---------------------------------------------------------------------------
// helpers
// ---------------------------------------------------------------------------
__device__ __forceinline__ unsigned short f2bf(float f) {
    __hip_bfloat16 h = __float2bfloat16(f);  // RNE
    return *reinterpret_cast<unsigned short*>(&h);
}
// unpack 8 bf16 (elem 2k in low 16 bits, 2k+1 in high) to f32
__device__ __forceinline__ void ub8(uint4 u, float* o) {
    o[0] = __uint_as_float(u.x << 16); o[1] = __uint_as_float(u.x & 0xffff0000u);
    o[2] = __uint_as_float(u.y << 16); o[3] = __uint_as_float(u.y & 0xffff0000u);
    o[4] = __uint_as_float(u.z << 16); o[5] = __uint_as_float(u.z & 0xffff0000u);
    o[6] = __uint_as_float(u.w << 16); o[7] = __uint_as_float(u.w & 0xffff0000u);
}

// ---------------------------------------------------------------------------
// prep: transpose img/temp to channel-interleaved bf16/f32 + grads; per-block
// Gram partials (f32 tree -> f64 write, NO atomics, NO fences).
// grid = B_*H_ blocks (one per (b,y) row), 256 threads (one per x).
// ---------------------------------------------------------------------------
__global__ __launch_bounds__(256) void prep_kernel(
    const float* __restrict__ img, const float* __restrict__ temp,
    uint4* __restrict__ imgT, uint4* __restrict__ TG,
    double* __restrict__ gramP) {
    __shared__ float smem[9472];   // rows: 8192 floats; reused for 256x37 reduce
    const int b   = blockIdx.x >> 8;
    const int y   = blockIdx.x & 255;
    const int tid = threadIdx.x;
    const int ym = (y > 0) ? y - 1 : 0;
    const int yp = (y < 255) ? y + 1 : 255;

    // stage 32 rows (8ch x {ym,y,yp,img-y}) as float4s: 2048 slots, 8/thread
    #pragma unroll
    for (int j = 0; j < 8; ++j) {
        const int slot = tid + 256 * j;
        const int rowid = slot >> 6, col4 = slot & 63;
        const int c = rowid >> 2, sel = rowid & 3;
        const int sy = (sel == 0) ? ym : ((sel == 2) ? yp : y);
        const float* src = ((sel == 3) ? img : temp)
                         + ((size_t)(b * K_ + c) * HW + sy * W_ + col4 * 4);
        const float4 v = *(const float4*)src;
        *(float4*)&smem[(c * 4 + sel) * 256 + col4 * 4] = v;
    }
    __syncthreads();

    const int x = tid;
    const int px = (y << 8) | x;
    const float X = (float)x - 127.5f, Y = (float)y - 127.5f;
    const int xm = (x > 0) ? x - 1 : 0;
    const int xp = (x < 255) ? x + 1 : 255;
    float Sxx = 0.f, Sxy = 0.f, Syy = 0.f;
    unsigned int imgp[4] = {0, 0, 0, 0};
    unsigned int tgp[16];
    #pragma unroll
    for (int i = 8; i < 16; ++i) tgp[i] = 0u;
    #pragma unroll
    for (int c = 0; c < 8; ++c) {
        const float* R = &smem[c * 1024];
        const float gx = 0.5f * (R[256 + xp] - R[256 + xm]);
        const float gy = 0.5f * (R[512 + x] - R[x]);
        const float tc = R[256 + x];
        const float iv = R[768 + x];
        Sxx += gx * gx; Sxy += gx * gy; Syy += gy * gy;
        const int sh = (c & 1) * 16;
        imgp[c >> 1]      |= ((unsigned int)f2bf(iv)) << sh;
        tgp[c]             = __float_as_uint(tc);
        tgp[8 + (c >> 1)] |= ((unsigned int)f2bf(gx)) << sh;
        tgp[12 + (c >> 1)]|= ((unsigned int)f2bf(gy)) << sh;
    }
    const size_t gpx = (size_t)b * HW + px;
    imgT[gpx] = make_uint4(imgp[0], imgp[1], imgp[2], imgp[3]);
    uint4* tg = TG + gpx * 4;
    tg[0] = make_uint4(tgp[0],  tgp[1],  tgp[2],  tgp[3]);
    tg[1] = make_uint4(tgp[4],  tgp[5],  tgp[6],  tgp[7]);
    tg[2] = make_uint4(tgp[8],  tgp[9],  tgp[10], tgp[11]);
    tg[3] = make_uint4(tgp[12], tgp[13], tgp[14], tgp[15]);
    __syncthreads();   // rows consumed; reuse smem for Gram reduce

    {   // expand (Sxx,Sxy,Syy) -> 36 upper-tri Gram entries via J = M(px)*(gx,gy)
        const float av[8] = {X, Y, 1.f, 0.f, 0.f, 0.f, -X * X, -X * Y};
        const float bv[8] = {0.f, 0.f, 0.f, X, Y, 1.f, -X * Y, -Y * Y};
        int idx = 0;
        #pragma unroll
        for (int pi = 0; pi < 8; ++pi)
            #pragma unroll
            for (int qi = pi; qi < 8; ++qi) {
                smem[tid * 37 + idx] = av[pi] * av[qi] * Sxx
                    + (av[pi] * bv[qi] + av[qi] * bv[pi]) * Sxy
                    + bv[pi] * bv[qi] * Syy;
                ++idx;
            }
    }
    __syncthreads();
    #pragma unroll
    for (int st = 128; st >= 1; st >>= 1) {
        if (tid < st) {
            #pragma unroll
            for (int e = 0; e < 36; ++e)
                smem[tid * 37 + e] += smem[(tid + st) * 37 + e];
        }
        __syncthreads();
    }
    if (tid < 36) gramP[(size_t)blockIdx.x * 36 + tid] = (double)smem[tid];
}

// ---------------------------------------------------------------------------
// invert: reduce gram partials (256 rows/batch) + f64 Gauss-Jordan -> invH.
// grid = B_ blocks, 64 threads.
// ---------------------------------------------------------------------------
__global__ void invert_kernel(const double* __restrict__ gramP,
                              double* __restrict__ invH) {
    const int b = blockIdx.x;
    const int t = threadIdx.x;
    __shared__ double G[36];
    __shared__ double A[64];
    __shared__ double Bi[64];
    if (t < 36) {
        double acc = 0.0;
        for (int r = 0; r < 256; ++r)
            acc += gramP[(size_t)(b * 256 + r) * 36 + t];
        G[t] = acc;
    }
    __syncthreads();
    const int i = t >> 3, j = t & 7;
    const int pp = min(i, j), qq = max(i, j);
    const int tri = 8 * pp - (pp * (pp - 1)) / 2 + (qq - pp);
    A[t]  = G[tri];
    Bi[t] = (i == j) ? 1.0 : 0.0;
    __syncthreads();
    for (int k = 0; k < 8; ++k) {
        const double piv = A[k * 8 + k];
        __syncthreads();
        if (i == k) { A[t] /= piv; Bi[t] /= piv; }
        __syncthreads();
        const double f  = A[i * 8 + k];
        const double ak = A[k * 8 + j];
        const double bk = Bi[k * 8 + j];
        __syncthreads();
        if (i != k) { A[t] -= f * ak; Bi[t] -= f * bk; }
        __syncthreads();
    }
    invH[b * 64 + t] = Bi[t];
}

// ---------------------------------------------------------------------------
// iter k: (1) reconstruct (p_k, dp_k) from previous partials (every block of
// the batch redundantly computes the identical update; designated block
// writes state); (2) warp + bilinear + residual -> per-block 8 partials.
// grid = B_*H_ blocks, 256 threads, 1 px/thread. No atomics, no fences.
// ---------------------------------------------------------------------------
__global__ __launch_bounds__(256) void iter_kernel(
    const uint4* __restrict__ imgT, const uint4* __restrict__ TG,
    const double* __restrict__ invH, const float* __restrict__ init_param,
    const double* __restrict__ stateR, double* __restrict__ stateW,
    const double* __restrict__ sPrev, double* __restrict__ sNext,
    const int* __restrict__ max_itr, int iter) {
    if (iter >= *max_itr) return;
    __shared__ double rd[256];
    __shared__ double sh_s[8];
    __shared__ double sh_pd[16];     // p_k (8) + dp_k (8)
    __shared__ double lds2[4][8];
    const int b   = blockIdx.x >> 8;
    const int tid = threadIdx.x;

    // ---- stage A: state reconstruction ----
    if (iter == 0) {
        if (tid < 8) {
            sh_pd[tid]     = (double)init_param[b * 8 + tid];
            sh_pd[8 + tid] = 1.0;
        }
    } else {
        const int g = tid >> 3, e = tid & 7;
        double v = 0.0;
        #pragma unroll
        for (int j = 0; j < 8; ++j)
            v += sPrev[(size_t)(b * 256 + g * 8 + j) * 8 + e];
        rd[tid] = v;
        __syncthreads();
        if (tid < 8) {
            double sv = 0.0;
            #pragma unroll
            for (int u = 0; u < 32; ++u) sv += rd[u * 8 + tid];
            sh_s[tid] = sv;
        }
        __syncthreads();
        if (tid < 8) {
            double nrm2 = 0.0;
            #pragma unroll
            for (int k2 = 0; k2 < 8; ++k2) {
                const double d = stateR[64 + b * 8 + k2];
                nrm2 += d * d;
            }
            double dpn = 0.0;
            if (tid < 6) {
                #pragma unroll
                for (int k2 = 0; k2 < 8; ++k2)
                    dpn += invH[b * 64 + tid * 8 + k2] * sh_s[k2];
            }
            const double dp2 = (sqrt(nrm2) > 1e-3) ? dpn : 0.0;
            sh_pd[tid]     = stateR[b * 8 + tid] - dp2;
            sh_pd[8 + tid] = dp2;
        }
    }
    __syncthreads();
    if ((blockIdx.x & 255) == 0 && tid < 8) {
        stateW[b * 8 + tid]      = sh_pd[tid];
        stateW[64 + b * 8 + tid] = sh_pd[8 + tid];
    }

    const float h00 = 1.f + (float)sh_pd[0], h01 = (float)sh_pd[1], h02 = (float)sh_pd[2];
    const float h10 = (float)sh_pd[3], h11 = 1.f + (float)sh_pd[4], h12 = (float)sh_pd[5];
    const float h20 = (float)sh_pd[6], h21 = (float)sh_pd[7];

    // ---- stage B: warp + bilinear + residual ----
    const int y = blockIdx.x & 255, x = tid;
    const int px = (y << 8) | x;
    const float X = (float)x - 127.5f, Y = (float)y - 127.5f;
    const float zw = h20 * X + h21 * Y + 1.f;
    const float Xw = (h00 * X + h01 * Y + h02) / zw + 127.5f;
    const float Yw = (h10 * X + h11 * Y + h12) / zw + 127.5f;
    const float NLO = -1.f + 2.f / 256.f, NHI = 1.f - 2.f / 256.f;
    const float xn = Xw / 127.5f - 1.f, yn = Yw / 127.5f - 1.f;
    const float m = (xn > NLO && xn < NHI && yn > NLO && yn < NHI) ? 1.f : 0.f;

    const float x0f = floorf(Xw), y0f = floorf(Yw);
    const float fx = Xw - x0f, fy = Yw - y0f;
    const float x1f = x0f + 1.f, y1f = y0f + 1.f;
    const bool vx0 = (x0f >= 0.f) && (x0f <= 255.f);
    const bool vx1 = (x1f >= 0.f) && (x1f <= 255.f);
    const bool vy0 = (y0f >= 0.f) && (y0f <= 255.f);
    const bool vy1 = (y1f >= 0.f) && (y1f <= 255.f);
    const int xi0 = (int)fminf(fmaxf(x0f, 0.f), 255.f);
    const int xi1 = (int)fminf(fmaxf(x1f, 0.f), 255.f);
    const int yi0 = (int)fminf(fmaxf(y0f, 0.f), 255.f);
    const int yi1 = (int)fminf(fmaxf(y1f, 0.f), 255.f);
    const int i00 = yi0 * W_ + xi0, i01 = yi0 * W_ + xi1;
    const int i10 = yi1 * W_ + xi0, i11 = yi1 * W_ + xi1;
    const float w00 = ((vx0 && vy0) ? 1.f : 0.f) * (1.f - fx) * (1.f - fy);
    const float w01 = ((vx1 && vy0) ? 1.f : 0.f) * fx * (1.f - fy);
    const float w10 = ((vx0 && vy1) ? 1.f : 0.f) * (1.f - fx) * fy;
    const float w11 = ((vx1 && vy1) ? 1.f : 0.f) * fx * fy;

    const int base = b * HW;
    const uint4 u00 = imgT[base + i00], u01 = imgT[base + i01];
    const uint4 u10 = imgT[base + i10], u11 = imgT[base + i11];
    const uint4* tg = TG + (size_t)(base + px) * 4;
    const uint4 t0 = tg[0], t1 = tg[1], g0 = tg[2], g1 = tg[3];

    float A00[8], A01[8], A10[8], A11[8], GX[8], GY[8], TV[8];
    ub8(u00, A00); ub8(u01, A01); ub8(u10, A10); ub8(u11, A11);
    ub8(g0, GX);   ub8(g1, GY);
    TV[0] = __uint_as_float(t0.x); TV[1] = __uint_as_float(t0.y);
    TV[2] = __uint_as_float(t0.z); TV[3] = __uint_as_float(t0.w);
    TV[4] = __uint_as_float(t1.x); TV[5] = __uint_as_float(t1.y);
    TV[6] = __uint_as_float(t1.z); TV[7] = __uint_as_float(t1.w);

    float vx = 0.f, vy = 0.f;
    #pragma unroll
    for (int c = 0; c < 8; ++c) {
        const float Q = w00 * A00[c] + w01 * A01[c] + w10 * A10[c] + w11 * A11[c];
        const float r = Q - TV[c] * m;
        vx += GX[c] * r;
        vy += GY[c] * r;
    }
    float a[8];
    a[0] = X * vx; a[1] = Y * vx; a[2] = vx;
    a[3] = X * vy; a[4] = Y * vy; a[5] = vy;
    const float cc = a[0] + a[4];
    a[6] = -X * cc; a[7] = -Y * cc;

    const int wave = tid >> 6, lane = tid & 63;
    #pragma unroll
    for (int e = 0; e < 8; ++e) {
        double v = (double)a[e];
        #pragma unroll
        for (int off = 32; off > 0; off >>= 1) v += __shfl_down(v, off, 64);
        if (lane == 0) lds2[wave][e] = v;
    }
    __syncthreads();
    if (tid < 8) {
        sNext[(size_t)blockIdx.x * 8 + tid] =
            lds2[0][tid] + lds2[1][tid] + lds2[2][tid] + lds2[3][tid];
    }
}

// ---------------------------------------------------------------------------
// output: final update (reduce last partials) + write p (64 f32) and H (72 f32)
// 1 block, 256 threads.
// ---------------------------------------------------------------------------
__global__ void output_kernel(const double* __restrict__ invH,
                              const float* __restrict__ init_param,
                              const double* __restrict__ st0,
                              const double* __restrict__ st1,
                              const double* __restrict__ sP0,
                              const double* __restrict__ sP1,
                              const int* __restrict__ max_itr,
                              float* __restrict__ out) {
    const int tid = threadIdx.x;
    const int mi_raw = *max_itr;
    const int mi = (mi_raw > 10) ? 10 : mi_raw;
    if (mi <= 0) {
        if (tid < 64) out[tid] = init_param[tid];
        if (tid < 72) {
            const int b = tid / 9, j = tid % 9;
            float v = (j < 8) ? init_param[b * 8 + j] : 0.f;
            if (j == 0 || j == 4 || j == 8) v += 1.f;
            out[64 + tid] = v;
        }
        return;
    }
    const int pr = (mi - 1) & 1;
    const double* st = pr ? st1 : st0;
    const double* sP = pr ? sP1 : sP0;
    __shared__ double rd[256];
    __shared__ double sh_s[8];
    __shared__ float  sh_pf[8];
    for (int b = 0; b < B_; ++b) {
        const int g = tid >> 3, e = tid & 7;
        double v = 0.0;
        #pragma unroll
        for (int j = 0; j < 8; ++j)
            v += sP[(size_t)(b * 256 + g * 8 + j) * 8 + e];
        rd[tid] = v;
        __syncthreads();
        if (tid < 8) {
            double sv = 0.0;
            #pragma unroll
            for (int u = 0; u < 32; ++u) sv += rd[u * 8 + tid];
            sh_s[tid] = sv;
        }
        __syncthreads();
        if (tid < 8) {
            double nrm2 = 0.0;
            #pragma unroll
            for (int k2 = 0; k2 < 8; ++k2) {
                const double d = st[64 + b * 8 + k2];
                nrm2 += d * d;
            }
            double dpn = 0.0;
            if (tid < 6) {
                #pragma unroll
                for (int k2 = 0; k2 < 8; ++k2)
                    dpn += invH[b * 64 + tid * 8 + k2] * sh_s[k2];
            }
            const double dp2 = (sqrt(nrm2) > 1e-3) ? dpn : 0.0;
            const float pf = (float)(st[b * 8 + tid] - dp2);
            sh_pf[tid] = pf;
            out[b * 8 + tid] = pf;
        }
        __syncthreads();
        if (tid < 9) {
            float v2 = (tid < 8) ? sh_pf[tid] : 0.f;
            if (tid == 0 || tid == 4 || tid == 8) v2 += 1.f;
            out[64 + b * 9 + tid] = v2;
        }
        __syncthreads();
    }
}

extern "C" void kernel_launch(void* const* d_in, const int* in_sizes, int n_in,
                              void* d_out, int out_size, void* d_ws, size_t ws_size,
                              hipStream_t stream) {
    const float* img        = (const float*)d_in[0];
    const float* temp       = (const float*)d_in[1];
    const float* init_param = (const float*)d_in[2];
    const int*   max_itr    = (const int*)d_in[3];
    float* out = (float*)d_out;

    char* w = (char*)d_ws;
    double* gramP = (double*)w;                  // 2048*36 = 73728 d (590 KB)
    double* invH  = gramP + 73728;               // 512 d
    double* st0   = invH + 512;                  // 128 d (p + dp)
    double* st1   = st0 + 128;                   // 128 d
    double* sP0   = st1 + 128;                   // 16384 d (128 KB)
    double* sP1   = sP0 + 16384;                 // 16384 d
    uint4* imgT   = (uint4*)(w + 1048576);           // 8.39 MB
    uint4* TG     = (uint4*)(w + 1048576 + 8388608); // 33.55 MB

    prep_kernel<<<B_ * H_, 256, 0, stream>>>(img, temp, imgT, TG, gramP);
    invert_kernel<<<B_, 64, 0, stream>>>(gramP, invH);
    for (int it = 0; it < 10; ++it) {
        const double* stR = (it & 1) ? st0 : st1;
        double*       stW = (it & 1) ? st1 : st0;
        const double* sR  = (it & 1) ? sP0 : sP1;
        double*       sW  = (it & 1) ? sP1 : sP0;
        iter_kernel<<<B_ * H_, 256, 0, stream>>>(imgT, TG, invH, init_param,
                                                 stR, stW, sR, sW, max_itr, it);
    }
    output_kernel<<<1, 256, 0, stream>>>(invH, init_param, st0, st1, sP0, sP1,
                                         max_itr, out);
}

// Round 5
// 199.673 us; speedup vs baseline: 9.8733x; 1.4300x over previous
//
#include <hip/hip_runtime.h>
#include <hip/hip_bf16.h>

#define B_ 8
#define K_ 8
#define H_ 256
#define W_ 256
#define HW (H_*W_)

// ---------------------------------------------------------------------------
// helpers
// ---------------------------------------------------------------------------
__device__ __forceinline__ unsigned short f2bf(float f) {
    __hip_bfloat16 h = __float2bfloat16(f);  // RNE
    return *reinterpret_cast<unsigned short*>(&h);
}
// unpack 8 bf16 (elem 2k in low 16 bits, 2k+1 in high) to f32
__device__ __forceinline__ void ub8(uint4 u, float* o) {
    o[0] = __uint_as_float(u.x << 16); o[1] = __uint_as_float(u.x & 0xffff0000u);
    o[2] = __uint_as_float(u.y << 16); o[3] = __uint_as_float(u.y & 0xffff0000u);
    o[4] = __uint_as_float(u.z << 16); o[5] = __uint_as_float(u.z & 0xffff0000u);
    o[6] = __uint_as_float(u.w << 16); o[7] = __uint_as_float(u.w & 0xffff0000u);
}
// sum across each 32-lane half; result valid in lanes 0 and 32
__device__ __forceinline__ float half_reduce(float v) {
    v += __shfl_down(v, 16, 64);
    v += __shfl_down(v, 8, 64);
    v += __shfl_down(v, 4, 64);
    v += __shfl_down(v, 2, 64);
    v += __shfl_down(v, 1, 64);
    return v;
}

// ---------------------------------------------------------------------------
// prep: transpose img/temp to channel-interleaved bf16 + grads; per-block
// Gram partials. grid = B_*H_ blocks (XCD-swizzled: b = blockIdx&7), 256 thr.
// ---------------------------------------------------------------------------
__global__ __launch_bounds__(256) void prep_kernel(
    const float* __restrict__ img, const float* __restrict__ temp,
    uint4* __restrict__ imgT, uint4* __restrict__ TG,
    double* __restrict__ gramP) {
    __shared__ float smem[9472];   // rows: 8192 floats; reused for 256x37 reduce
    const int b   = blockIdx.x & 7;
    const int y   = blockIdx.x >> 3;
    const int tid = threadIdx.x;
    const int ym = (y > 0) ? y - 1 : 0;
    const int yp = (y < 255) ? y + 1 : 255;

    // stage 32 rows (8ch x {ym,y,yp,img-y}) as float4s: 2048 slots, 8/thread
    #pragma unroll
    for (int j = 0; j < 8; ++j) {
        const int slot = tid + 256 * j;
        const int rowid = slot >> 6, col4 = slot & 63;
        const int c = rowid >> 2, sel = rowid & 3;
        const int sy = (sel == 0) ? ym : ((sel == 2) ? yp : y);
        const float* src = ((sel == 3) ? img : temp)
                         + ((size_t)(b * K_ + c) * HW + sy * W_ + col4 * 4);
        const float4 v = *(const float4*)src;
        *(float4*)&smem[(c * 4 + sel) * 256 + col4 * 4] = v;
    }
    __syncthreads();

    const int x = tid;
    const int px = (y << 8) | x;
    const float X = (float)x - 127.5f, Y = (float)y - 127.5f;
    const int xm = (x > 0) ? x - 1 : 0;
    const int xp = (x < 255) ? x + 1 : 255;
    float Sxx = 0.f, Sxy = 0.f, Syy = 0.f;
    unsigned int imgp[4] = {0, 0, 0, 0};
    unsigned int tgp[12];
    #pragma unroll
    for (int i = 0; i < 12; ++i) tgp[i] = 0u;
    #pragma unroll
    for (int c = 0; c < 8; ++c) {
        const float* R = &smem[c * 1024];
        const float gx = 0.5f * (R[256 + xp] - R[256 + xm]);
        const float gy = 0.5f * (R[512 + x] - R[x]);
        const float tc = R[256 + x];
        const float iv = R[768 + x];
        Sxx += gx * gx; Sxy += gx * gy; Syy += gy * gy;
        const int sh = (c & 1) * 16;
        imgp[c >> 1]     |= ((unsigned int)f2bf(iv)) << sh;
        tgp[c >> 1]      |= ((unsigned int)f2bf(tc)) << sh;
        tgp[4 + (c >> 1)]|= ((unsigned int)f2bf(gx)) << sh;
        tgp[8 + (c >> 1)]|= ((unsigned int)f2bf(gy)) << sh;
    }
    const size_t gpx = (size_t)b * HW + px;
    imgT[gpx] = make_uint4(imgp[0], imgp[1], imgp[2], imgp[3]);
    uint4* tg = TG + gpx * 3;
    tg[0] = make_uint4(tgp[0], tgp[1], tgp[2],  tgp[3]);
    tg[1] = make_uint4(tgp[4], tgp[5], tgp[6],  tgp[7]);
    tg[2] = make_uint4(tgp[8], tgp[9], tgp[10], tgp[11]);
    __syncthreads();   // rows consumed; reuse smem for Gram reduce

    {   // expand (Sxx,Sxy,Syy) -> 36 upper-tri Gram entries via J = M(px)*(gx,gy)
        const float av[8] = {X, Y, 1.f, 0.f, 0.f, 0.f, -X * X, -X * Y};
        const float bv[8] = {0.f, 0.f, 0.f, X, Y, 1.f, -X * Y, -Y * Y};
        int idx = 0;
        #pragma unroll
        for (int pi = 0; pi < 8; ++pi)
            #pragma unroll
            for (int qi = pi; qi < 8; ++qi) {
                smem[tid * 37 + idx] = av[pi] * av[qi] * Sxx
                    + (av[pi] * bv[qi] + av[qi] * bv[pi]) * Sxy
                    + bv[pi] * bv[qi] * Syy;
                ++idx;
            }
    }
    __syncthreads();
    #pragma unroll
    for (int st = 128; st >= 1; st >>= 1) {
        if (tid < st) {
            #pragma unroll
            for (int e = 0; e < 36; ++e)
                smem[tid * 37 + e] += smem[(tid + st) * 37 + e];
        }
        __syncthreads();
    }
    if (tid < 36) gramP[(size_t)(b * 256 + y) * 36 + tid] = (double)smem[tid];
}

// ---------------------------------------------------------------------------
// invert: reduce gram partials (256 rows/batch) + f64 Gauss-Jordan -> invH.
// grid = B_ blocks, 64 threads.
// ---------------------------------------------------------------------------
__global__ void invert_kernel(const double* __restrict__ gramP,
                              double* __restrict__ invH) {
    const int b = blockIdx.x;
    const int t = threadIdx.x;
    __shared__ double G[36];
    __shared__ double A[64];
    __shared__ double Bi[64];
    if (t < 36) {
        double acc = 0.0;
        for (int r = 0; r < 256; ++r)
            acc += gramP[(size_t)(b * 256 + r) * 36 + t];
        G[t] = acc;
    }
    __syncthreads();
    const int i = t >> 3, j = t & 7;
    const int pp = min(i, j), qq = max(i, j);
    const int tri = 8 * pp - (pp * (pp - 1)) / 2 + (qq - pp);
    A[t]  = G[tri];
    Bi[t] = (i == j) ? 1.0 : 0.0;
    __syncthreads();
    for (int k = 0; k < 8; ++k) {
        const double piv = A[k * 8 + k];
        __syncthreads();
        if (i == k) { A[t] /= piv; Bi[t] /= piv; }
        __syncthreads();
        const double f  = A[i * 8 + k];
        const double ak = A[k * 8 + j];
        const double bk = Bi[k * 8 + j];
        __syncthreads();
        if (i != k) { A[t] -= f * ak; Bi[t] -= f * bk; }
        __syncthreads();
    }
    invH[b * 64 + t] = Bi[t];
}

// ---------------------------------------------------------------------------
// iter k: (1) reconstruct (p_k, dp_k) from previous f32 transposed partials
// (redundantly per block; designated block writes state); (2) warp + bilinear
// + residual -> per-block 8 f32 partials (transposed). No atomics, no fences.
// grid = B_*H_ blocks (XCD-swizzled), 256 threads, 1 px/thread.
// ---------------------------------------------------------------------------
__global__ __launch_bounds__(256) void iter_kernel(
    const uint4* __restrict__ imgT, const uint4* __restrict__ TG,
    const double* __restrict__ invH, const float* __restrict__ init_param,
    const double* __restrict__ stateR, double* __restrict__ stateW,
    const float* __restrict__ sPrevT, float* __restrict__ sNextT,
    const int* __restrict__ max_itr, int iter) {
    if (iter >= *max_itr) return;
    __shared__ float red[2048];
    __shared__ float s8[8];
    __shared__ double sh_pd[16];     // p_k (8) + dp_k (8)
    const int b   = blockIdx.x & 7;
    const int y   = blockIdx.x >> 3;
    const int tid = threadIdx.x;

    // ---- stage A: state reconstruction ----
    if (iter == 0) {
        if (tid < 8) {
            sh_pd[tid]     = (double)init_param[b * 8 + tid];
            sh_pd[8 + tid] = 1.0;
        }
    } else {
        const float* sb = sPrevT + b * 2048;
        const float4 u0 = *(const float4*)(sb + tid * 8);
        const float4 u1 = *(const float4*)(sb + tid * 8 + 4);
        float v = ((u0.x + u0.y) + (u0.z + u0.w)) + ((u1.x + u1.y) + (u1.z + u1.w));
        v = half_reduce(v);                     // entry e = tid>>5
        if ((tid & 31) == 0) s8[tid >> 5] = v;
        __syncthreads();
        if (tid < 8) {
            double nrm2 = 0.0;
            #pragma unroll
            for (int k2 = 0; k2 < 8; ++k2) {
                const double d = stateR[64 + b * 8 + k2];
                nrm2 += d * d;
            }
            double dpn = 0.0;
            if (tid < 6) {
                #pragma unroll
                for (int k2 = 0; k2 < 8; ++k2)
                    dpn += invH[b * 64 + tid * 8 + k2] * (double)s8[k2];
            }
            const double dp2 = (sqrt(nrm2) > 1e-3) ? dpn : 0.0;
            sh_pd[tid]     = stateR[b * 8 + tid] - dp2;
            sh_pd[8 + tid] = dp2;
        }
    }
    __syncthreads();
    if (y == 0 && tid < 8) {
        stateW[b * 8 + tid]      = sh_pd[tid];
        stateW[64 + b * 8 + tid] = sh_pd[8 + tid];
    }

    const float h00 = 1.f + (float)sh_pd[0], h01 = (float)sh_pd[1], h02 = (float)sh_pd[2];
    const float h10 = (float)sh_pd[3], h11 = 1.f + (float)sh_pd[4], h12 = (float)sh_pd[5];
    const float h20 = (float)sh_pd[6], h21 = (float)sh_pd[7];

    // ---- stage B: warp + bilinear + residual ----
    const int x = tid;
    const int px = (y << 8) | x;
    const float X = (float)x - 127.5f, Y = (float)y - 127.5f;
    const float zw = h20 * X + h21 * Y + 1.f;
    const float Xw = (h00 * X + h01 * Y + h02) / zw + 127.5f;
    const float Yw = (h10 * X + h11 * Y + h12) / zw + 127.5f;
    const float NLO = -1.f + 2.f / 256.f, NHI = 1.f - 2.f / 256.f;
    const float xn = Xw / 127.5f - 1.f, yn = Yw / 127.5f - 1.f;
    const float m = (xn > NLO && xn < NHI && yn > NLO && yn < NHI) ? 1.f : 0.f;

    const float x0f = floorf(Xw), y0f = floorf(Yw);
    const float fx = Xw - x0f, fy = Yw - y0f;
    const float x1f = x0f + 1.f, y1f = y0f + 1.f;
    const bool vx0 = (x0f >= 0.f) && (x0f <= 255.f);
    const bool vx1 = (x1f >= 0.f) && (x1f <= 255.f);
    const bool vy0 = (y0f >= 0.f) && (y0f <= 255.f);
    const bool vy1 = (y1f >= 0.f) && (y1f <= 255.f);
    const int xi0 = (int)fminf(fmaxf(x0f, 0.f), 255.f);
    const int xi1 = (int)fminf(fmaxf(x1f, 0.f), 255.f);
    const int yi0 = (int)fminf(fmaxf(y0f, 0.f), 255.f);
    const int yi1 = (int)fminf(fmaxf(y1f, 0.f), 255.f);
    const int i00 = yi0 * W_ + xi0, i01 = yi0 * W_ + xi1;
    const int i10 = yi1 * W_ + xi0, i11 = yi1 * W_ + xi1;
    const float w00 = ((vx0 && vy0) ? 1.f : 0.f) * (1.f - fx) * (1.f - fy);
    const float w01 = ((vx1 && vy0) ? 1.f : 0.f) * fx * (1.f - fy);
    const float w10 = ((vx0 && vy1) ? 1.f : 0.f) * (1.f - fx) * fy;
    const float w11 = ((vx1 && vy1) ? 1.f : 0.f) * fx * fy;

    const int base = b * HW;
    const uint4 u00 = imgT[base + i00], u01 = imgT[base + i01];
    const uint4 u10 = imgT[base + i10], u11 = imgT[base + i11];
    const uint4* tg = TG + (size_t)(base + px) * 3;
    const uint4 t0 = tg[0], g0 = tg[1], g1 = tg[2];

    float A00[8], A01[8], A10[8], A11[8], GX[8], GY[8], TV[8];
    ub8(u00, A00); ub8(u01, A01); ub8(u10, A10); ub8(u11, A11);
    ub8(t0, TV);   ub8(g0, GX);   ub8(g1, GY);

    float vx = 0.f, vy = 0.f;
    #pragma unroll
    for (int c = 0; c < 8; ++c) {
        const float Q = w00 * A00[c] + w01 * A01[c] + w10 * A10[c] + w11 * A11[c];
        const float r = Q - TV[c] * m;
        vx += GX[c] * r;
        vy += GY[c] * r;
    }
    float a[8];
    a[0] = X * vx; a[1] = Y * vx; a[2] = vx;
    a[3] = X * vy; a[4] = Y * vy; a[5] = vy;
    const float cc = a[0] + a[4];
    a[6] = -X * cc; a[7] = -Y * cc;

    // ---- block reduce: [e][256] scatter -> strided read -> 32-lane shfl ----
    #pragma unroll
    for (int e = 0; e < 8; ++e) red[e * 256 + tid] = a[e];
    __syncthreads();
    {
        const int e = tid >> 5, l = tid & 31;
        float v = 0.f;
        #pragma unroll
        for (int j = 0; j < 8; ++j) v += red[e * 256 + l + 32 * j];
        v = half_reduce(v);
        if ((tid & 31) == 0) s8[tid >> 5] = v;
    }
    __syncthreads();
    if (tid < 8) sNextT[b * 2048 + tid * 256 + y] = s8[tid];
}

// ---------------------------------------------------------------------------
// output: final update (reduce last partials) + write p (64 f32), H (72 f32)
// 1 block, 256 threads.
// ---------------------------------------------------------------------------
__global__ void output_kernel(const double* __restrict__ invH,
                              const float* __restrict__ init_param,
                              const double* __restrict__ st0,
                              const double* __restrict__ st1,
                              const float* __restrict__ sT0,
                              const float* __restrict__ sT1,
                              const int* __restrict__ max_itr,
                              float* __restrict__ out) {
    const int tid = threadIdx.x;
    const int mi_raw = *max_itr;
    const int mi = (mi_raw > 10) ? 10 : mi_raw;
    if (mi <= 0) {
        if (tid < 64) out[tid] = init_param[tid];
        if (tid < 72) {
            const int b = tid / 9, j = tid % 9;
            float v = (j < 8) ? init_param[b * 8 + j] : 0.f;
            if (j == 0 || j == 4 || j == 8) v += 1.f;
            out[64 + tid] = v;
        }
        return;
    }
    const int pr = (mi - 1) & 1;
    const double* st = pr ? st1 : st0;
    const float*  sT = pr ? sT1 : sT0;
    __shared__ float s8[8];
    __shared__ float sh_pf[8];
    for (int b = 0; b < B_; ++b) {
        const float* sb = sT + b * 2048;
        const float4 u0 = *(const float4*)(sb + tid * 8);
        const float4 u1 = *(const float4*)(sb + tid * 8 + 4);
        float v = ((u0.x + u0.y) + (u0.z + u0.w)) + ((u1.x + u1.y) + (u1.z + u1.w));
        v = half_reduce(v);
        if ((tid & 31) == 0) s8[tid >> 5] = v;
        __syncthreads();
        if (tid < 8) {
            double nrm2 = 0.0;
            #pragma unroll
            for (int k2 = 0; k2 < 8; ++k2) {
                const double d = st[64 + b * 8 + k2];
                nrm2 += d * d;
            }
            double dpn = 0.0;
            if (tid < 6) {
                #pragma unroll
                for (int k2 = 0; k2 < 8; ++k2)
                    dpn += invH[b * 64 + tid * 8 + k2] * (double)s8[k2];
            }
            const double dp2 = (sqrt(nrm2) > 1e-3) ? dpn : 0.0;
            const float pf = (float)(st[b * 8 + tid] - dp2);
            sh_pf[tid] = pf;
            out[b * 8 + tid] = pf;
        }
        __syncthreads();
        if (tid < 9) {
            float v2 = (tid < 8) ? sh_pf[tid] : 0.f;
            if (tid == 0 || tid == 4 || tid == 8) v2 += 1.f;
            out[64 + b * 9 + tid] = v2;
        }
        __syncthreads();
    }
}

extern "C" void kernel_launch(void* const* d_in, const int* in_sizes, int n_in,
                              void* d_out, int out_size, void* d_ws, size_t ws_size,
                              hipStream_t stream) {
    const float* img        = (const float*)d_in[0];
    const float* temp       = (const float*)d_in[1];
    const float* init_param = (const float*)d_in[2];
    const int*   max_itr    = (const int*)d_in[3];
    float* out = (float*)d_out;

    char* w = (char*)d_ws;
    double* gramP = (double*)w;                  // 2048*36 d = 576 KB
    double* invH  = gramP + 73728;               // 512 d
    double* st0   = invH + 512;                  // 128 d (p + dp)
    double* st1   = st0 + 128;                   // 128 d
    float*  sT0   = (float*)(st1 + 128);         // 8*2048 f32 = 64 KB
    float*  sT1   = sT0 + 16384;                 // 64 KB
    uint4* imgT   = (uint4*)(w + 1048576);           // 8.39 MB (bf16 x8 per px)
    uint4* TG     = (uint4*)(w + 1048576 + 8388608); // 25.2 MB (T,gx,gy bf16 x8)

    prep_kernel<<<B_ * H_, 256, 0, stream>>>(img, temp, imgT, TG, gramP);
    invert_kernel<<<B_, 64, 0, stream>>>(gramP, invH);
    for (int it = 0; it < 10; ++it) {
        const double* stR = (it & 1) ? st0 : st1;
        double*       stW = (it & 1) ? st1 : st0;
        const float*  sR  = (it & 1) ? sT0 : sT1;
        float*        sW  = (it & 1) ? sT1 : sT0;
        iter_kernel<<<B_ * H_, 256, 0, stream>>>(imgT, TG, invH, init_param,
                                                 stR, stW, sR, sW, max_itr, it);
    }
    output_kernel<<<1, 256, 0, stream>>>(invH, init_param, st0, st1, sT0, sT1,
                                         max_itr, out);
}